// Round 1
// baseline (779.021 us; speedup 1.0000x reference)
//
#include <hip/hip_runtime.h>

typedef _Float16 half8 __attribute__((ext_vector_type(8)));
typedef float floatx16 __attribute__((ext_vector_type(16)));

constexpr int Gn = 5;
constexpr int Bn = 131072;
constexpr int Kn = 512;
constexpr int Dn = 64;

constexpr long long QOFF = (long long)Gn * Bn * Dn;  // end of quantized block
constexpr long long IOFF = QOFF + Gn + 1;            // start of indices block
constexpr unsigned CAPE = 49152;                     // rescue-entry capacity

// ---------------------------------------------------------------------------
// Fused prep: esq (bit-exact round-1 accumulation order — rescue depends on
// it), split-fp16 codebook (ch16 = fp16(c), cl16 = fp16((c-ch)*2048)), and
// esqh = fp16(-esq*1024) — the bias row that folds -esq/2 into the MFMA via
// a 2^-11 B-slot (1024 * 2^-11 = 1/2).
// ---------------------------------------------------------------------------
__global__ void vq_prep(const float* __restrict__ code, float* __restrict__ esq,
                        _Float16* __restrict__ ch16, _Float16* __restrict__ cl16,
                        _Float16* __restrict__ esqh) {
    int i = blockIdx.x * blockDim.x + threadIdx.x;
    if (i >= Gn * Kn) return;
    const float4* c4 = reinterpret_cast<const float4*>(code + (long long)i * Dn);
    _Float16* hp = ch16 + (long long)i * Dn;
    _Float16* lp = cl16 + (long long)i * Dn;
    float s0 = 0.f, s1 = 0.f, s2 = 0.f, s3 = 0.f;
#pragma unroll
    for (int j = 0; j < 16; ++j) {
        float4 v = c4[j];
        s0 += v.x * v.x; s1 += v.y * v.y; s2 += v.z * v.z; s3 += v.w * v.w;
        _Float16 hx = (_Float16)v.x, hy = (_Float16)v.y;
        _Float16 hz = (_Float16)v.z, hw = (_Float16)v.w;
        hp[4 * j + 0] = hx; hp[4 * j + 1] = hy;
        hp[4 * j + 2] = hz; hp[4 * j + 3] = hw;
        lp[4 * j + 0] = (_Float16)((v.x - (float)hx) * 2048.0f);
        lp[4 * j + 1] = (_Float16)((v.y - (float)hy) * 2048.0f);
        lp[4 * j + 2] = (_Float16)((v.z - (float)hz) * 2048.0f);
        lp[4 * j + 3] = (_Float16)((v.w - (float)hw) * 2048.0f);
    }
    float e = (s0 + s1) + (s2 + s3);
    esq[i] = e;
    esqh[i] = (_Float16)(-(e * 1024.0f));
}

// ---------------------------------------------------------------------------
// Transposed-MFMA screening. A = codebook chunk (m = code), B = features
// (n = feature row). acc = dot - esq/2 accumulated in ONE chain:
//   4x mfma(cH, fH) + 4x mfma(cL*2^11, fH*2^-11) + 1x bias mfma.
// Each lane's 16 acc values = 16 codes of ONE feature row -> top-2 is two
// scalar regs (med3 + max), 8-bit (chunk<<4|reg) id packed in mantissa LSBs,
// one shfl_xor(32) merge across the two half-wave code subsets at the end.
// 32 rows/wave, 4 waves/block, no LDS, no cross-chunk register arrays.
// ---------------------------------------------------------------------------
__global__ __launch_bounds__(256, 3) void vq_screen(
    const float* __restrict__ feat, const float* __restrict__ codef,
    const _Float16* __restrict__ ch16, const _Float16* __restrict__ cl16,
    const _Float16* __restrict__ esqh, float* __restrict__ out,
    float* __restrict__ accg, unsigned* __restrict__ cnt,
    unsigned* __restrict__ entries)
{
    const int g = blockIdx.y;
    const int lane = threadIdx.x & 63;
    const int wv = threadIdx.x >> 6;
    const int l31 = lane & 31;
    const int hh = lane >> 5;
    const long long rowbase = (long long)blockIdx.x * 128 + wv * 32;
    const float MARGIN = 5.0e-5f;   // gap in (dot - esq/2) units; 13-sigma vs
                                    // missing c*fL rms ~3.7e-6 + 8-bit pack ~2e-6
    const int CLR = (int)0xFFFFFF00;

    // ---- feature staging: fH = fp16(f), fHs = fH * 2^-11 (exact), xsq -----
    // B layout 32x32x16: n = lane&31 (row), k = 8*hh + j + 16*s
    half8 fH[4], fHs[4];
    const float* rp = feat + ((long long)g * Bn + rowbase + l31) * Dn + hh * 8;
    float xs = 0.f;
#pragma unroll
    for (int s = 0; s < 4; ++s) {
        float4 u0 = *(const float4*)(rp + 16 * s);
        float4 u1 = *(const float4*)(rp + 16 * s + 4);
        half8 h;
        h[0] = (_Float16)u0.x; h[1] = (_Float16)u0.y;
        h[2] = (_Float16)u0.z; h[3] = (_Float16)u0.w;
        h[4] = (_Float16)u1.x; h[5] = (_Float16)u1.y;
        h[6] = (_Float16)u1.z; h[7] = (_Float16)u1.w;
        fH[s] = h;
        fHs[s] = h * (_Float16)4.8828125e-4f;   // * 2^-11, exponent-exact
        xs += u0.x*u0.x + u0.y*u0.y + u0.z*u0.z + u0.w*u0.w
            + u1.x*u1.x + u1.y*u1.y + u1.z*u1.z + u1.w*u1.w;
    }
    xs += __shfl_xor(xs, 32);

    // bias B-frag: 2^-11 in k==0 slot (hh==0, j==0), zero elsewhere
    half8 b5 = {(_Float16)0.f};
    b5[0] = hh ? (_Float16)0.f : (_Float16)4.8828125e-4f;

    // ---- codebook bases; chunk = 32 codes, 16 chunks ----------------------
    const _Float16* bh = ch16 + ((long long)g * Kn + l31) * Dn + hh * 8;
    const _Float16* bl = cl16 + ((long long)g * Kn + l31) * Dn + hh * 8;
    const _Float16* ep = esqh + g * Kn + l31;

    half8 cH[4], cLs[4];
#pragma unroll
    for (int s = 0; s < 4; ++s) {
        cH[s]  = *(const half8*)(bh + 16 * s);
        cLs[s] = *(const half8*)(bl + 16 * s);
    }
    _Float16 a5v = ep[0];

    float v1 = -3.0e38f, v2 = -3.0e38f;

    for (int ch = 0; ch < 16; ++ch) {
        half8 nH[4], nLs[4];
        _Float16 na5 = (_Float16)0.f;
        if (ch < 15) {
            const _Float16* ph = bh + (ch + 1) * 2048;
            const _Float16* pl = bl + (ch + 1) * 2048;
#pragma unroll
            for (int s = 0; s < 4; ++s) {
                nH[s]  = *(const half8*)(ph + 16 * s);
                nLs[s] = *(const half8*)(pl + 16 * s);
            }
            na5 = ep[(ch + 1) * 32];
        }
        half8 a5 = {(_Float16)0.f};
        a5[0] = hh ? (_Float16)0.f : a5v;   // -esq*1024 in k==0 slot

        floatx16 acc = {0.f};
#pragma unroll
        for (int s = 0; s < 4; ++s)
            acc = __builtin_amdgcn_mfma_f32_32x32x16_f16(cH[s], fH[s], acc, 0, 0, 0);
#pragma unroll
        for (int s = 0; s < 4; ++s)
            acc = __builtin_amdgcn_mfma_f32_32x32x16_f16(cLs[s], fHs[s], acc, 0, 0, 0);
        acc = __builtin_amdgcn_mfma_f32_32x32x16_f16(a5, b5, acc, 0, 0, 0);
        // acc[r] = dot(code, fH_row) - esq[code]/2   (codebook side exact)

        const int idb = ch << 4;
#pragma unroll
        for (int r = 0; r < 16; ++r) {
            float cd = __int_as_float((__float_as_int(acc[r]) & CLR) | (idb | r));
            v2 = __builtin_amdgcn_fmed3f(v1, v2, cd);   // new 2nd-max
            v1 = fmaxf(v1, cd);                          // new max
        }
        if (ch < 15) {
#pragma unroll
            for (int s = 0; s < 4; ++s) { cH[s] = nH[s]; cLs[s] = nLs[s]; }
            a5v = na5;
        }
    }

    // ---- merge the two half-wave code subsets (same feature row) ----------
    float o1 = __shfl_xor(v1, 32);
    float o2 = __shfl_xor(v2, 32);
    float w1 = fmaxf(v1, o1);
    float w2 = fmaxf(fminf(v1, o1), fmaxf(v2, o2));
    int hsrc = (o1 > v1) ? (hh ^ 1) : hh;      // equal packed => same code
    int idw = __float_as_int(w1) & 255;
    int rr  = idw & 15;
    // C/D row map: code_in_chunk = (r&3) + 8*(r>>2) + 4*hh_src
    int code = ((idw >> 4) << 5) + (rr & 3) + 8 * (rr >> 2) + 4 * hsrc;
    float v1c = __int_as_float(__float_as_int(w1) & CLR);
    float v2c = __int_as_float(__float_as_int(w2) & CLR);

    // ---- epilogue: gather quantized (each lane writes its hh half) --------
    const long long grow = rowbase + l31;
    const float* qsrc = codef + ((long long)(g * Kn + code)) * Dn + hh * 32;
    float* qdst = out + ((long long)g * Bn + grow) * Dn + hh * 32;
#pragma unroll
    for (int q = 0; q < 8; ++q)
        *(float4*)(qdst + 4 * q) = *(const float4*)(qsrc + 4 * q);

    float lsum = 0.f;
    bool fl = false;
    if (hh == 0) {
        out[IOFF + (long long)g * Bn + grow] = (float)code;
        lsum = xs - 2.0f * v1c;               // xsq + esq - 2*dot
        fl = (v1c - v2c <= MARGIN);
    }

    // ---- wave-aggregated rescue-entry append (<=1 atomic per wave) --------
    unsigned long long m0 = __ballot(fl);
    unsigned tot = (unsigned)__builtin_popcountll(m0);
    if (tot) {
        unsigned base = 0;
        if (lane == 0) base = atomicAdd(cnt, tot);
        base = (unsigned)__shfl((int)base, 0);
        if (fl) {
            unsigned long long lt = ((unsigned long long)1 << lane) - 1;
            unsigned s = base + (unsigned)__builtin_popcountll(m0 & lt);
            if (s < CAPE) entries[s] = ((unsigned)g << 17) | (unsigned)grow;
        }
    }
#pragma unroll
    for (int m = 1; m < 64; m <<= 1) lsum += __shfl_xor(lsum, m);
    if (lane == 0) atomicAdd(&accg[g], lsum);
}

// ---------------------------------------------------------------------------
// Exact rescue: one wave per flagged row, full K=512 scan with round-1's
// bit-exact fp32 formula (pairwise-8 xsq, 4-acc fmaf dot, first-index ties).
// Finalize fused in (block 0 lane 0) — acc is complete before this launch.
// ---------------------------------------------------------------------------
__global__ __launch_bounds__(256) void vq_rescue(
    const float* __restrict__ feat, const float* __restrict__ codef,
    const float* __restrict__ esq, const unsigned* __restrict__ cnt,
    const unsigned* __restrict__ entries, float* __restrict__ out,
    const float* __restrict__ accg)
{
    if (blockIdx.x == 0 && threadIdx.x == 0) {
        float tot = 0.f;
#pragma unroll
        for (int g = 0; g < Gn; ++g) {
            float m = accg[g] / 8388608.0f;
            float l = m + 0.25f * m;
            out[QOFF + g] = l;
            tot += l;
        }
        out[QOFF + Gn] = tot;
    }

    const int lane = threadIdx.x & 63;
    const int wid = blockIdx.x * 4 + (threadIdx.x >> 6);
    const int nw = gridDim.x * 4;
    const int n = (int)min(*cnt, CAPE);

    for (int i = wid; i < n; i += nw) {
        unsigned e = entries[i];
        int g = e >> 17;
        long long b = e & 131071u;

        const float* xp = feat + ((long long)g * Bn + b) * Dn;
        float x[64];
#pragma unroll
        for (int j = 0; j < 16; ++j) {
            float4 u = ((const float4*)xp)[j];
            x[4*j] = u.x; x[4*j+1] = u.y; x[4*j+2] = u.z; x[4*j+3] = u.w;
        }
        float xsq;
        {
#pragma clang fp contract(off)
            float r0[8];
#pragma unroll
            for (int j = 0; j < 8; ++j) r0[j] = x[j] * x[j];
#pragma unroll
            for (int q = 8; q < 64; q += 8)
#pragma unroll
                for (int j = 0; j < 8; ++j) {
                    float s0 = x[q + j] * x[q + j];
                    r0[j] = r0[j] + s0;
                }
            xsq = ((r0[0] + r0[1]) + (r0[2] + r0[3])) + ((r0[4] + r0[5]) + (r0[6] + r0[7]));
        }

        const float* cg = codef + (long long)g * Kn * Dn;
        const float* eg = esq + g * Kn;
        float best = 3.4e38f; int bk = 0x7fffffff;
        for (int j = 0; j < 8; ++j) {
            int k = j * 64 + lane;
            const float4* cp = (const float4*)(cg + (long long)k * Dn);
            float d0 = 0.f, d1 = 0.f, d2 = 0.f, d3 = 0.f;
#pragma unroll
            for (int q = 0; q < 16; ++q) {
                float4 v = cp[q];
                d0 = fmaf(v.x, x[4*q+0], d0);
                d1 = fmaf(v.y, x[4*q+1], d1);
                d2 = fmaf(v.z, x[4*q+2], d2);
                d3 = fmaf(v.w, x[4*q+3], d3);
            }
            float dot = (d0 + d1) + (d2 + d3);
            float dist = (xsq + eg[k]) - 2.0f * dot;
            if (dist < best) { best = dist; bk = k; }
        }
#pragma unroll
        for (int m = 1; m < 64; m <<= 1) {
            float ov = __shfl_xor(best, m);
            int   ok = __shfl_xor(bk, m);
            if (ov < best || (ov == best && ok < bk)) { best = ov; bk = ok; }
        }
        if (lane == 0) out[IOFF + (long long)g * Bn + b] = (float)bk;
        out[((long long)g * Bn + b) * Dn + lane] = cg[(long long)bk * Dn + lane];
    }
}

extern "C" void kernel_launch(void* const* d_in, const int* in_sizes, int n_in,
                              void* d_out, int out_size, void* d_ws, size_t ws_size,
                              hipStream_t stream) {
    const float* feat = (const float*)d_in[0];   // [G,B,D] fp32
    const float* code = (const float*)d_in[1];   // [G,K,D] fp32
    float* out = (float*)d_out;

    char* w = (char*)d_ws;
    float*     acc     = (float*)w;                    // [0,64)
    unsigned*  cnt     = (unsigned*)(w + 64);          // [64,128)
    float*     esq     = (float*)(w + 128);            // 10240 B
    _Float16*  esqh    = (_Float16*)(w + 10368);       // 5120 B
    _Float16*  ch16    = (_Float16*)(w + 15488);       // 327680 B (16B-aligned)
    _Float16*  cl16    = (_Float16*)(w + 343168);      // 327680 B (16B-aligned)
    unsigned*  entries = (unsigned*)(w + 670848);      // 49152*4 = 196608 B (total 867456)

    hipMemsetAsync(w, 0, 128, stream);
    vq_prep<<<(Gn * Kn + 255) / 256, 256, 0, stream>>>(code, esq, ch16, cl16, esqh);
    dim3 grid(Bn / 128, Gn);
    vq_screen<<<grid, 256, 0, stream>>>(feat, code, ch16, cl16, esqh, out, acc, cnt, entries);
    vq_rescue<<<2048, 256, 0, stream>>>(feat, code, esq, cnt, entries, out, acc);
}

// Round 3
// 567.818 us; speedup vs baseline: 1.3720x; 1.3720x over previous
//
#include <hip/hip_runtime.h>

typedef _Float16 half8 __attribute__((ext_vector_type(8)));
typedef float floatx16 __attribute__((ext_vector_type(16)));

constexpr int Gn = 5;
constexpr int Bn = 131072;
constexpr int Kn = 512;
constexpr int Dn = 64;

constexpr long long QOFF = (long long)Gn * Bn * Dn;  // end of quantized block
constexpr long long IOFF = QOFF + Gn + 1;            // start of indices block
constexpr unsigned CAPE = 49152;                     // rescue-entry capacity

// ---------------------------------------------------------------------------
// Prep: esq (bit-exact round-1 accumulation order — rescue depends on it),
// fp16 codebook ch16 (linear layout), and esqt = fp16(-esq*1024) stored
// TRANSPOSED: esqt[g][code&31][code>>5] so screen loads 16 chunk-values of
// its code-slot as one contiguous 32B read. Bias folds -esq/2 into the MFMA
// via a 2^-11 B-slot (1024 * 2^-11 = 1/2).
// No cl16 low-half: residual x*dc error (~1.1e-6 rms) is the same order as
// the c*dx error all prior rounds already carried; MARGIN covers it.
// ---------------------------------------------------------------------------
__global__ void vq_prep(const float* __restrict__ code, float* __restrict__ esq,
                        _Float16* __restrict__ ch16, _Float16* __restrict__ esqt) {
    int i = blockIdx.x * blockDim.x + threadIdx.x;
    if (i >= Gn * Kn) return;
    const float4* c4 = reinterpret_cast<const float4*>(code + (long long)i * Dn);
    _Float16* hp = ch16 + (long long)i * Dn;
    float s0 = 0.f, s1 = 0.f, s2 = 0.f, s3 = 0.f;
#pragma unroll
    for (int j = 0; j < 16; ++j) {
        float4 v = c4[j];
        s0 += v.x * v.x; s1 += v.y * v.y; s2 += v.z * v.z; s3 += v.w * v.w;
        hp[4 * j + 0] = (_Float16)v.x;
        hp[4 * j + 1] = (_Float16)v.y;
        hp[4 * j + 2] = (_Float16)v.z;
        hp[4 * j + 3] = (_Float16)v.w;
    }
    float e = (s0 + s1) + (s2 + s3);
    esq[i] = e;
    int g = i >> 9, k = i & 511;
    esqt[(g << 9) + ((k & 31) << 4) + (k >> 5)] = (_Float16)(-(e * 1024.0f));
}

// ---------------------------------------------------------------------------
// LDS-staged transposed-MFMA screening.
//   A = codebook chunk (m = code, from LDS), B = two feature tiles (n = row).
//   acc_t = dot - esq/2 via 4 dot MFMAs + 1 bias MFMA, two independent
//   chains (t = 0,1) for ILP. 64 rows/wave, 4 waves share each staged chunk.
// LDS: 2 x 4KB double buffer, 16B units XOR-swizzled (unit ^= code&7) so
//   ds_read_b128 fragment reads are in the verified conflict-free class.
// Pipeline: iter ch issues global loads for ch+2 (regs), ds_writes ch+1,
//   ds_reads + computes ch; ONE barrier per chunk.
// Tracking: per lane top-2 scalars (med3+max), 8-bit (chunk<<4|reg) id in
//   mantissa LSBs, one shfl_xor(32) merge at the end.
// Epilogue: coalesced gather (shfl-broadcast winner per row, 4 rows/iter,
//   1KB contiguous stores).
// ---------------------------------------------------------------------------
__global__ __launch_bounds__(256, 3) void vq_screen(
    const float* __restrict__ feat, const float* __restrict__ codef,
    const _Float16* __restrict__ ch16, const _Float16* __restrict__ esqt,
    float* __restrict__ out, float* __restrict__ accg,
    unsigned* __restrict__ cnt, unsigned* __restrict__ entries)
{
    __shared__ float4 smf[2 * 256];   // [buf][32 codes][8 units] = 2 x 4KB

    const int g = blockIdx.y;
    const int lane = threadIdx.x & 63;
    const int wv = threadIdx.x >> 6;
    const int l31 = lane & 31;
    const int hh = lane >> 5;
    const long long rowbase = (long long)blockIdx.x * 256 + wv * 64;
    const float MARGIN = 3.0e-5f;   // mdist units; err-diff rms ~2.1e-6 -> 14 sigma
    const int CLR = (int)0xFFFFFF00;

    // ---- feature staging: 2 tiles x 32 rows; B layout n=l31, k=8*hh+j+16*s
    half8 fH[2][4]; float xs[2];
#pragma unroll
    for (int t = 0; t < 2; ++t) {
        const float* rp = feat + ((long long)g * Bn + rowbase + t * 32 + l31) * Dn + hh * 8;
        float x = 0.f;
#pragma unroll
        for (int s = 0; s < 4; ++s) {
            float4 u0 = *(const float4*)(rp + 16 * s);
            float4 u1 = *(const float4*)(rp + 16 * s + 4);
            half8 h;
            h[0] = (_Float16)u0.x; h[1] = (_Float16)u0.y;
            h[2] = (_Float16)u0.z; h[3] = (_Float16)u0.w;
            h[4] = (_Float16)u1.x; h[5] = (_Float16)u1.y;
            h[6] = (_Float16)u1.z; h[7] = (_Float16)u1.w;
            fH[t][s] = h;
            x += u0.x*u0.x + u0.y*u0.y + u0.z*u0.z + u0.w*u0.w
               + u1.x*u1.x + u1.y*u1.y + u1.z*u1.z + u1.w*u1.w;
        }
        xs[t] = x + __shfl_xor(x, 32);
    }

    // ---- esq bias values: 16 chunk-values for this lane's code slot -------
    const half8* evp = (const half8*)(esqt + ((long long)g << 9) + l31 * 16);
    half8 ev0 = evp[0], ev1 = evp[1];

    // bias B-frag: 2^-11 in k==0 slot (hh==0, j==0), zero elsewhere
    half8 b5 = {(_Float16)0.f};
    b5[0] = hh ? (_Float16)0.f : (_Float16)4.8828125e-4f;

    // ---- staging addresses ------------------------------------------------
    const int cs = lane >> 3;            // 0..7: code sub-index in wave's 8 codes
    const int u  = lane & 7;             // 16B unit within code row
    const int codeLocal = wv * 8 + cs;   // 0..31 (codeLocal & 7 == cs)
    const float4* srcF4 = (const float4*)(ch16 + ((long long)g * Kn) * Dn);
    const int srcIdx = codeLocal * 8 + u;          // + ch*256 per chunk
    const int dstIdx = codeLocal * 8 + (u ^ cs);   // swizzled LDS unit
    const int rb0 = l31 * 8;
    const int rsw = l31 & 7;

    // ---- prologue: chunk0 -> buf0; chunk1 -> regs -------------------------
    float4 sreg[16];
    sreg[0] = srcF4[srcIdx];
    smf[dstIdx] = sreg[0];
    sreg[1] = srcF4[srcIdx + 256];
    __syncthreads();

    float v1[2] = {-3.0e38f, -3.0e38f}, v2[2] = {-3.0e38f, -3.0e38f};

#pragma unroll
    for (int ch = 0; ch < 16; ++ch) {
        const int buf = (ch & 1) * 256;
        if (ch + 2 < 16) sreg[ch + 2] = srcF4[srcIdx + (ch + 2) * 256];
        if (ch + 1 < 16) smf[((ch + 1) & 1) * 256 + dstIdx] = sreg[ch + 1];

        half8 cH[4];
#pragma unroll
        for (int s = 0; s < 4; ++s)
            cH[s] = *(const half8*)&smf[buf + rb0 + ((hh + 2 * s) ^ rsw)];

        half8 a5 = {(_Float16)0.f};
        _Float16 eb = (ch < 8) ? ev0[ch] : ev1[ch - 8];
        a5[0] = hh ? (_Float16)0.f : eb;   // -esq*1024 in k==0 slot

        floatx16 acc0 = {0.f}, acc1 = {0.f};
#pragma unroll
        for (int s = 0; s < 4; ++s) {
            acc0 = __builtin_amdgcn_mfma_f32_32x32x16_f16(cH[s], fH[0][s], acc0, 0, 0, 0);
            acc1 = __builtin_amdgcn_mfma_f32_32x32x16_f16(cH[s], fH[1][s], acc1, 0, 0, 0);
        }
        acc0 = __builtin_amdgcn_mfma_f32_32x32x16_f16(a5, b5, acc0, 0, 0, 0);
        acc1 = __builtin_amdgcn_mfma_f32_32x32x16_f16(a5, b5, acc1, 0, 0, 0);

        const int idb = ch << 4;
#pragma unroll
        for (int r = 0; r < 16; ++r) {
            float c0 = __int_as_float((__float_as_int(acc0[r]) & CLR) | (idb | r));
            v2[0] = __builtin_amdgcn_fmed3f(v1[0], v2[0], c0);
            v1[0] = fmaxf(v1[0], c0);
            float c1 = __int_as_float((__float_as_int(acc1[r]) & CLR) | (idb | r));
            v2[1] = __builtin_amdgcn_fmed3f(v1[1], v2[1], c1);
            v1[1] = fmaxf(v1[1], c1);
        }
        __syncthreads();
    }

    // ---- merge the two half-wave code subsets (same feature row) ----------
    int codew[2]; float v1c[2], v2c[2];
#pragma unroll
    for (int t = 0; t < 2; ++t) {
        float o1 = __shfl_xor(v1[t], 32);
        float o2 = __shfl_xor(v2[t], 32);
        float w1 = fmaxf(v1[t], o1);
        float w2 = fmaxf(fminf(v1[t], o1), fmaxf(v2[t], o2));
        int hsrc = (o1 > v1[t]) ? (hh ^ 1) : hh;   // equal packed => same (ch,r), flagged anyway
        int idw = __float_as_int(w1) & 255;
        int rr = idw & 15;
        // C/D row map: code_in_chunk = (r&3) + 8*(r>>2) + 4*hh_src
        codew[t] = ((idw >> 4) << 5) + (rr & 3) + 8 * (rr >> 2) + 4 * hsrc;
        v1c[t] = __int_as_float(__float_as_int(w1) & CLR);
        v2c[t] = __int_as_float(__float_as_int(w2) & CLR);
    }

    // ---- epilogue: coalesced gather (4 rows / iter, 1KB contiguous stores)
#pragma unroll
    for (int t = 0; t < 2; ++t) {
        float* obase = out + ((long long)g * Bn + rowbase + t * 32) * Dn;
#pragma unroll
        for (int i = 0; i < 8; ++i) {
            int r = i * 4 + (lane >> 4);
            int c = __shfl(codew[t], r);   // owner lane r (hh=0 copy)
            float4 q = *(const float4*)(codef + ((long long)(g * Kn + c)) * Dn + (lane & 15) * 4);
            *(float4*)(obase + (long long)r * Dn + (lane & 15) * 4) = q;
        }
    }

    // ---- indices, loss, rescue flags --------------------------------------
    float lsum = 0.f;
    bool fl[2] = {false, false};
    unsigned rw[2] = {0u, 0u};
#pragma unroll
    for (int t = 0; t < 2; ++t) {
        if (hh == 0) {
            long long grow = rowbase + t * 32 + l31;
            out[IOFF + (long long)g * Bn + grow] = (float)codew[t];
            lsum += xs[t] - 2.0f * v1c[t];            // xsq + esq - 2*dot
            fl[t] = (v1c[t] - v2c[t] <= MARGIN);
            rw[t] = (unsigned)grow;
        }
    }

    // ---- wave-aggregated rescue-entry append (<=1 atomic per wave) --------
    unsigned long long m0 = __ballot(fl[0]);
    unsigned long long m1 = __ballot(fl[1]);
    unsigned tot = (unsigned)(__builtin_popcountll(m0) + __builtin_popcountll(m1));
    if (tot) {
        unsigned base = 0;
        if (lane == 0) base = atomicAdd(cnt, tot);
        base = (unsigned)__shfl((int)base, 0);
        unsigned long long lt = ((unsigned long long)1 << lane) - 1;
        if (fl[0]) {
            unsigned s = base + (unsigned)__builtin_popcountll(m0 & lt);
            if (s < CAPE) entries[s] = ((unsigned)g << 17) | rw[0];
        }
        if (fl[1]) {
            unsigned s = base + (unsigned)__builtin_popcountll(m0)
                              + (unsigned)__builtin_popcountll(m1 & lt);
            if (s < CAPE) entries[s] = ((unsigned)g << 17) | rw[1];
        }
    }
#pragma unroll
    for (int m = 1; m < 64; m <<= 1) lsum += __shfl_xor(lsum, m);
    if (lane == 0) atomicAdd(&accg[g], lsum);
}

// ---------------------------------------------------------------------------
// Exact rescue: one wave per flagged row, full K=512 scan with round-1's
// bit-exact fp32 formula (pairwise-8 xsq, 4-acc fmaf dot, first-index ties).
// Finalize fused in (block 0 lane 0) — acc is complete before this launch.
// ---------------------------------------------------------------------------
__global__ __launch_bounds__(256) void vq_rescue(
    const float* __restrict__ feat, const float* __restrict__ codef,
    const float* __restrict__ esq, const unsigned* __restrict__ cnt,
    const unsigned* __restrict__ entries, float* __restrict__ out,
    const float* __restrict__ accg)
{
    if (blockIdx.x == 0 && threadIdx.x == 0) {
        float tot = 0.f;
#pragma unroll
        for (int g = 0; g < Gn; ++g) {
            float m = accg[g] / 8388608.0f;
            float l = m + 0.25f * m;
            out[QOFF + g] = l;
            tot += l;
        }
        out[QOFF + Gn] = tot;
    }

    const int lane = threadIdx.x & 63;
    const int wid = blockIdx.x * 4 + (threadIdx.x >> 6);
    const int nw = gridDim.x * 4;
    const int n = (int)min(*cnt, CAPE);

    for (int i = wid; i < n; i += nw) {
        unsigned e = entries[i];
        int g = e >> 17;
        long long b = e & 131071u;

        const float* xp = feat + ((long long)g * Bn + b) * Dn;
        float x[64];
#pragma unroll
        for (int j = 0; j < 16; ++j) {
            float4 u = ((const float4*)xp)[j];
            x[4*j] = u.x; x[4*j+1] = u.y; x[4*j+2] = u.z; x[4*j+3] = u.w;
        }
        float xsq;
        {
#pragma clang fp contract(off)
            float r0[8];
#pragma unroll
            for (int j = 0; j < 8; ++j) r0[j] = x[j] * x[j];
#pragma unroll
            for (int q = 8; q < 64; q += 8)
#pragma unroll
                for (int j = 0; j < 8; ++j) {
                    float s0 = x[q + j] * x[q + j];
                    r0[j] = r0[j] + s0;
                }
            xsq = ((r0[0] + r0[1]) + (r0[2] + r0[3])) + ((r0[4] + r0[5]) + (r0[6] + r0[7]));
        }

        const float* cg = codef + (long long)g * Kn * Dn;
        const float* eg = esq + g * Kn;
        float best = 3.4e38f; int bk = 0x7fffffff;
        for (int j = 0; j < 8; ++j) {
            int k = j * 64 + lane;
            const float4* cp = (const float4*)(cg + (long long)k * Dn);
            float d0 = 0.f, d1 = 0.f, d2 = 0.f, d3 = 0.f;
#pragma unroll
            for (int q = 0; q < 16; ++q) {
                float4 v = cp[q];
                d0 = fmaf(v.x, x[4*q+0], d0);
                d1 = fmaf(v.y, x[4*q+1], d1);
                d2 = fmaf(v.z, x[4*q+2], d2);
                d3 = fmaf(v.w, x[4*q+3], d3);
            }
            float dot = (d0 + d1) + (d2 + d3);
            float dist = (xsq + eg[k]) - 2.0f * dot;
            if (dist < best) { best = dist; bk = k; }
        }
#pragma unroll
        for (int m = 1; m < 64; m <<= 1) {
            float ov = __shfl_xor(best, m);
            int   ok = __shfl_xor(bk, m);
            if (ov < best || (ov == best && ok < bk)) { best = ov; bk = ok; }
        }
        if (lane == 0) out[IOFF + (long long)g * Bn + b] = (float)bk;
        out[((long long)g * Bn + b) * Dn + lane] = cg[(long long)bk * Dn + lane];
    }
}

extern "C" void kernel_launch(void* const* d_in, const int* in_sizes, int n_in,
                              void* d_out, int out_size, void* d_ws, size_t ws_size,
                              hipStream_t stream) {
    const float* feat = (const float*)d_in[0];   // [G,B,D] fp32
    const float* code = (const float*)d_in[1];   // [G,K,D] fp32
    float* out = (float*)d_out;

    char* w = (char*)d_ws;
    float*     acc     = (float*)w;                    // [0,64)
    unsigned*  cnt     = (unsigned*)(w + 64);          // [64,128)
    float*     esq     = (float*)(w + 128);            // 10240 B
    _Float16*  esqt    = (_Float16*)(w + 10368);       // 5120 B (16B-aligned)
    _Float16*  ch16    = (_Float16*)(w + 15488);       // 327680 B (16B-aligned)
    unsigned*  entries = (unsigned*)(w + 343168);      // 49152*4 = 196608 B (total 539776)

    hipMemsetAsync(w, 0, 128, stream);
    vq_prep<<<(Gn * Kn + 255) / 256, 256, 0, stream>>>(code, esq, ch16, esqt);
    dim3 grid(Bn / 256, Gn);
    vq_screen<<<grid, 256, 0, stream>>>(feat, code, ch16, esqt, out, acc, cnt, entries);
    vq_rescue<<<2048, 256, 0, stream>>>(feat, code, esq, cnt, entries, out, acc);
}

// Round 4
// 525.018 us; speedup vs baseline: 1.4838x; 1.0815x over previous
//
#include <hip/hip_runtime.h>

typedef _Float16 half8 __attribute__((ext_vector_type(8)));
typedef float floatx16 __attribute__((ext_vector_type(16)));

constexpr int Gn = 5;
constexpr int Bn = 131072;
constexpr int Kn = 512;
constexpr int Dn = 64;

constexpr long long QOFF = (long long)Gn * Bn * Dn;  // end of quantized block
constexpr long long IOFF = QOFF + Gn + 1;            // start of indices block
constexpr unsigned CAPE = 49152;                     // rescue-entry capacity

// async global->LDS, 16B per lane; dest = wave-uniform base + lane*16
#define GLDS(gp, lp)  __builtin_amdgcn_global_load_lds( \
    (const __attribute__((address_space(1))) void*)(gp), \
    (__attribute__((address_space(3))) void*)(lp), 16, 0, 0)

// ---------------------------------------------------------------------------
// Prep: esq (bit-exact round-1 accumulation order — rescue depends on it),
// fp16 codebook ch16 (linear layout), and esqt = fp16(-esq*1024) stored
// TRANSPOSED: esqt[g][code&31][code>>5] so screen loads 16 chunk-values of
// its code-slot as one contiguous 32B read. Bias folds -esq/2 into the MFMA
// via a 2^-11 B-slot (1024 * 2^-11 = 1/2).
// ---------------------------------------------------------------------------
__global__ void vq_prep(const float* __restrict__ code, float* __restrict__ esq,
                        _Float16* __restrict__ ch16, _Float16* __restrict__ esqt) {
    int i = blockIdx.x * blockDim.x + threadIdx.x;
    if (i >= Gn * Kn) return;
    const float4* c4 = reinterpret_cast<const float4*>(code + (long long)i * Dn);
    _Float16* hp = ch16 + (long long)i * Dn;
    float s0 = 0.f, s1 = 0.f, s2 = 0.f, s3 = 0.f;
#pragma unroll
    for (int j = 0; j < 16; ++j) {
        float4 v = c4[j];
        s0 += v.x * v.x; s1 += v.y * v.y; s2 += v.z * v.z; s3 += v.w * v.w;
        hp[4 * j + 0] = (_Float16)v.x;
        hp[4 * j + 1] = (_Float16)v.y;
        hp[4 * j + 2] = (_Float16)v.z;
        hp[4 * j + 3] = (_Float16)v.w;
    }
    float e = (s0 + s1) + (s2 + s3);
    esq[i] = e;
    int g = i >> 9, k = i & 511;
    esqt[(g << 9) + ((k & 31) << 4) + (k >> 5)] = (_Float16)(-(e * 1024.0f));
}

// ---------------------------------------------------------------------------
// LDS-staged transposed-MFMA screening, global_load_lds edition.
//   A = codebook chunk (m = code, from LDS), B = two feature tiles (n = row).
//   acc_t = dot - esq/2 via 4 dot MFMAs + 1 bias MFMA, two independent
//   chains for ILP. 64 rows/wave, 4 waves share each staged chunk.
// Staging: global_load_lds width=16, double-buffered, 1 chunk ahead.
//   Swizzle is applied on the GLOBAL source address (u^cs involution); LDS
//   dest is linear (wave base + lane*16 -> unit codeLocal*8+u), so the LDS
//   content layout is identical to the reg-staged round-3 kernel and all
//   ds_read addressing is unchanged. No VGPR staging array -> no scratch.
//   The compiler's vmcnt(0) drain before each s_barrier is exactly the wait
//   this 1-ahead pipeline needs.
// Tracking: per lane top-2 scalars (med3+max), 8-bit (chunk<<4|reg) id in
//   mantissa LSBs, one shfl_xor(32) merge at the end.
// ---------------------------------------------------------------------------
__global__ __launch_bounds__(256, 4) void vq_screen(
    const float* __restrict__ feat, const float* __restrict__ codef,
    const _Float16* __restrict__ ch16, const _Float16* __restrict__ esqt,
    float* __restrict__ out, float* __restrict__ accg,
    unsigned* __restrict__ cnt, unsigned* __restrict__ entries)
{
    __shared__ float4 smf[2 * 256];   // [buf][32 codes][8 units] = 2 x 4KB

    const int g = blockIdx.y;
    const int lane = threadIdx.x & 63;
    const int wv = threadIdx.x >> 6;
    const int l31 = lane & 31;
    const int hh = lane >> 5;
    const long long rowbase = (long long)blockIdx.x * 256 + wv * 64;
    const float MARGIN = 3.0e-5f;   // mdist units; err-diff rms ~5e-6 -> ~6 sigma
    const int CLR = (int)0xFFFFFF00;

    // ---- feature staging: 2 tiles x 32 rows; B layout n=l31, k=8*hh+j+16*s
    half8 fH[2][4]; float xs[2];
#pragma unroll
    for (int t = 0; t < 2; ++t) {
        const float* rp = feat + ((long long)g * Bn + rowbase + t * 32 + l31) * Dn + hh * 8;
        float x = 0.f;
#pragma unroll
        for (int s = 0; s < 4; ++s) {
            float4 u0 = *(const float4*)(rp + 16 * s);
            float4 u1 = *(const float4*)(rp + 16 * s + 4);
            half8 h;
            h[0] = (_Float16)u0.x; h[1] = (_Float16)u0.y;
            h[2] = (_Float16)u0.z; h[3] = (_Float16)u0.w;
            h[4] = (_Float16)u1.x; h[5] = (_Float16)u1.y;
            h[6] = (_Float16)u1.z; h[7] = (_Float16)u1.w;
            fH[t][s] = h;
            x += u0.x*u0.x + u0.y*u0.y + u0.z*u0.z + u0.w*u0.w
               + u1.x*u1.x + u1.y*u1.y + u1.z*u1.z + u1.w*u1.w;
        }
        xs[t] = x + __shfl_xor(x, 32);
    }

    // ---- esq bias values: 16 chunk-values for this lane's code slot -------
    const half8* evp = (const half8*)(esqt + ((long long)g << 9) + l31 * 16);
    half8 ev0 = evp[0], ev1 = evp[1];

    // bias B-frag: 2^-11 in k==0 slot (hh==0, j==0), zero elsewhere
    half8 b5 = {(_Float16)0.f};
    b5[0] = hh ? (_Float16)0.f : (_Float16)4.8828125e-4f;

    // ---- staging addresses ------------------------------------------------
    const int cs = lane >> 3;            // 0..7: code sub-index in wave's 8 codes
    const int u  = lane & 7;             // 16B unit within code row
    const int codeLocal = wv * 8 + cs;   // 0..31 (codeLocal & 7 == cs)
    const float4* srcF4 = (const float4*)(ch16 + ((long long)g * Kn) * Dn);
    // pre-swizzled global source; LDS dest linear (unit codeLocal*8 + u)
    const float4* gsrc = srcF4 + codeLocal * 8 + (u ^ cs);
    const int rb0 = l31 * 8;
    const int rsw = l31 & 7;

    // ---- prologue: chunk0 -> buf0 ----------------------------------------
    GLDS(gsrc, &smf[wv * 64]);
    __syncthreads();   // compiler drains vmcnt(0) before the barrier

    float v1[2] = {-3.0e38f, -3.0e38f}, v2[2] = {-3.0e38f, -3.0e38f};

#pragma unroll
    for (int ch = 0; ch < 16; ++ch) {
        const int buf = (ch & 1) * 256;
        if (ch + 1 < 16)
            GLDS(gsrc + (ch + 1) * 256, &smf[((ch + 1) & 1) * 256 + wv * 64]);

        half8 cH[4];
#pragma unroll
        for (int s = 0; s < 4; ++s)
            cH[s] = *(const half8*)&smf[buf + rb0 + ((hh + 2 * s) ^ rsw)];

        half8 a5 = {(_Float16)0.f};
        _Float16 eb = (ch < 8) ? ev0[ch] : ev1[ch - 8];
        a5[0] = hh ? (_Float16)0.f : eb;   // -esq*1024 in k==0 slot

        floatx16 acc0 = {0.f}, acc1 = {0.f};
#pragma unroll
        for (int s = 0; s < 4; ++s) {
            acc0 = __builtin_amdgcn_mfma_f32_32x32x16_f16(cH[s], fH[0][s], acc0, 0, 0, 0);
            acc1 = __builtin_amdgcn_mfma_f32_32x32x16_f16(cH[s], fH[1][s], acc1, 0, 0, 0);
        }
        acc0 = __builtin_amdgcn_mfma_f32_32x32x16_f16(a5, b5, acc0, 0, 0, 0);
        acc1 = __builtin_amdgcn_mfma_f32_32x32x16_f16(a5, b5, acc1, 0, 0, 0);

        const int idb = ch << 4;
#pragma unroll
        for (int r = 0; r < 16; ++r) {
            float c0 = __int_as_float((__float_as_int(acc0[r]) & CLR) | (idb | r));
            v2[0] = __builtin_amdgcn_fmed3f(v1[0], v2[0], c0);
            v1[0] = fmaxf(v1[0], c0);
            float c1 = __int_as_float((__float_as_int(acc1[r]) & CLR) | (idb | r));
            v2[1] = __builtin_amdgcn_fmed3f(v1[1], v2[1], c1);
            v1[1] = fmaxf(v1[1], c1);
        }
        __syncthreads();   // protects buf reuse; drains next-chunk loads
    }

    // ---- merge the two half-wave code subsets (same feature row) ----------
    int codew[2]; float v1c[2], v2c[2];
#pragma unroll
    for (int t = 0; t < 2; ++t) {
        float o1 = __shfl_xor(v1[t], 32);
        float o2 = __shfl_xor(v2[t], 32);
        float w1 = fmaxf(v1[t], o1);
        float w2 = fmaxf(fminf(v1[t], o1), fmaxf(v2[t], o2));
        int hsrc = (o1 > v1[t]) ? (hh ^ 1) : hh;   // equal packed => same (ch,r), flagged anyway
        int idw = __float_as_int(w1) & 255;
        int rr = idw & 15;
        // C/D row map: code_in_chunk = (r&3) + 8*(r>>2) + 4*hh_src
        codew[t] = ((idw >> 4) << 5) + (rr & 3) + 8 * (rr >> 2) + 4 * hsrc;
        v1c[t] = __int_as_float(__float_as_int(w1) & CLR);
        v2c[t] = __int_as_float(__float_as_int(w2) & CLR);
    }

    // ---- epilogue: coalesced gather (4 rows / iter, 1KB contiguous stores)
#pragma unroll
    for (int t = 0; t < 2; ++t) {
        float* obase = out + ((long long)g * Bn + rowbase + t * 32) * Dn;
#pragma unroll
        for (int i = 0; i < 8; ++i) {
            int r = i * 4 + (lane >> 4);
            int c = __shfl(codew[t], r);   // owner lane r (hh=0 copy)
            float4 q = *(const float4*)(codef + ((long long)(g * Kn + c)) * Dn + (lane & 15) * 4);
            *(float4*)(obase + (long long)r * Dn + (lane & 15) * 4) = q;
        }
    }

    // ---- indices, loss, rescue flags --------------------------------------
    float lsum = 0.f;
    bool fl[2] = {false, false};
    unsigned rw[2] = {0u, 0u};
#pragma unroll
    for (int t = 0; t < 2; ++t) {
        if (hh == 0) {
            long long grow = rowbase + t * 32 + l31;
            out[IOFF + (long long)g * Bn + grow] = (float)codew[t];
            lsum += xs[t] - 2.0f * v1c[t];            // xsq + esq - 2*dot
            fl[t] = (v1c[t] - v2c[t] <= MARGIN);
            rw[t] = (unsigned)grow;
        }
    }

    // ---- wave-aggregated rescue-entry append (<=1 atomic per wave) --------
    unsigned long long m0 = __ballot(fl[0]);
    unsigned long long m1 = __ballot(fl[1]);
    unsigned tot = (unsigned)(__builtin_popcountll(m0) + __builtin_popcountll(m1));
    if (tot) {
        unsigned base = 0;
        if (lane == 0) base = atomicAdd(cnt, tot);
        base = (unsigned)__shfl((int)base, 0);
        unsigned long long lt = ((unsigned long long)1 << lane) - 1;
        if (fl[0]) {
            unsigned s = base + (unsigned)__builtin_popcountll(m0 & lt);
            if (s < CAPE) entries[s] = ((unsigned)g << 17) | rw[0];
        }
        if (fl[1]) {
            unsigned s = base + (unsigned)__builtin_popcountll(m0)
                              + (unsigned)__builtin_popcountll(m1 & lt);
            if (s < CAPE) entries[s] = ((unsigned)g << 17) | rw[1];
        }
    }
#pragma unroll
    for (int m = 1; m < 64; m <<= 1) lsum += __shfl_xor(lsum, m);
    if (lane == 0) atomicAdd(&accg[g], lsum);
}

// ---------------------------------------------------------------------------
// Exact rescue: one wave per flagged row, full K=512 scan with round-1's
// bit-exact fp32 formula (pairwise-8 xsq, 4-acc fmaf dot, first-index ties).
// Finalize fused in (block 0 lane 0) — acc is complete before this launch.
// ---------------------------------------------------------------------------
__global__ __launch_bounds__(256) void vq_rescue(
    const float* __restrict__ feat, const float* __restrict__ codef,
    const float* __restrict__ esq, const unsigned* __restrict__ cnt,
    const unsigned* __restrict__ entries, float* __restrict__ out,
    const float* __restrict__ accg)
{
    if (blockIdx.x == 0 && threadIdx.x == 0) {
        float tot = 0.f;
#pragma unroll
        for (int g = 0; g < Gn; ++g) {
            float m = accg[g] / 8388608.0f;
            float l = m + 0.25f * m;
            out[QOFF + g] = l;
            tot += l;
        }
        out[QOFF + Gn] = tot;
    }

    const int lane = threadIdx.x & 63;
    const int wid = blockIdx.x * 4 + (threadIdx.x >> 6);
    const int nw = gridDim.x * 4;
    const int n = (int)min(*cnt, CAPE);

    for (int i = wid; i < n; i += nw) {
        unsigned e = entries[i];
        int g = e >> 17;
        long long b = e & 131071u;

        const float* xp = feat + ((long long)g * Bn + b) * Dn;
        float x[64];
#pragma unroll
        for (int j = 0; j < 16; ++j) {
            float4 u = ((const float4*)xp)[j];
            x[4*j] = u.x; x[4*j+1] = u.y; x[4*j+2] = u.z; x[4*j+3] = u.w;
        }
        float xsq;
        {
#pragma clang fp contract(off)
            float r0[8];
#pragma unroll
            for (int j = 0; j < 8; ++j) r0[j] = x[j] * x[j];
#pragma unroll
            for (int q = 8; q < 64; q += 8)
#pragma unroll
                for (int j = 0; j < 8; ++j) {
                    float s0 = x[q + j] * x[q + j];
                    r0[j] = r0[j] + s0;
                }
            xsq = ((r0[0] + r0[1]) + (r0[2] + r0[3])) + ((r0[4] + r0[5]) + (r0[6] + r0[7]));
        }

        const float* cg = codef + (long long)g * Kn * Dn;
        const float* eg = esq + g * Kn;
        float best = 3.4e38f; int bk = 0x7fffffff;
        for (int j = 0; j < 8; ++j) {
            int k = j * 64 + lane;
            const float4* cp = (const float4*)(cg + (long long)k * Dn);
            float d0 = 0.f, d1 = 0.f, d2 = 0.f, d3 = 0.f;
#pragma unroll
            for (int q = 0; q < 16; ++q) {
                float4 v = cp[q];
                d0 = fmaf(v.x, x[4*q+0], d0);
                d1 = fmaf(v.y, x[4*q+1], d1);
                d2 = fmaf(v.z, x[4*q+2], d2);
                d3 = fmaf(v.w, x[4*q+3], d3);
            }
            float dot = (d0 + d1) + (d2 + d3);
            float dist = (xsq + eg[k]) - 2.0f * dot;
            if (dist < best) { best = dist; bk = k; }
        }
#pragma unroll
        for (int m = 1; m < 64; m <<= 1) {
            float ov = __shfl_xor(best, m);
            int   ok = __shfl_xor(bk, m);
            if (ov < best || (ov == best && ok < bk)) { best = ov; bk = ok; }
        }
        if (lane == 0) out[IOFF + (long long)g * Bn + b] = (float)bk;
        out[((long long)g * Bn + b) * Dn + lane] = cg[(long long)bk * Dn + lane];
    }
}

extern "C" void kernel_launch(void* const* d_in, const int* in_sizes, int n_in,
                              void* d_out, int out_size, void* d_ws, size_t ws_size,
                              hipStream_t stream) {
    const float* feat = (const float*)d_in[0];   // [G,B,D] fp32
    const float* code = (const float*)d_in[1];   // [G,K,D] fp32
    float* out = (float*)d_out;

    char* w = (char*)d_ws;
    float*     acc     = (float*)w;                    // [0,64)
    unsigned*  cnt     = (unsigned*)(w + 64);          // [64,128)
    float*     esq     = (float*)(w + 128);            // 10240 B
    _Float16*  esqt    = (_Float16*)(w + 10368);       // 5120 B (16B-aligned)
    _Float16*  ch16    = (_Float16*)(w + 15488);       // 327680 B (16B-aligned)
    unsigned*  entries = (unsigned*)(w + 343168);      // 49152*4 = 196608 B (total 539776)

    hipMemsetAsync(w, 0, 128, stream);
    vq_prep<<<(Gn * Kn + 255) / 256, 256, 0, stream>>>(code, esq, ch16, esqt);
    dim3 grid(Bn / 256, Gn);
    vq_screen<<<grid, 256, 0, stream>>>(feat, code, ch16, esqt, out, acc, cnt, entries);
    vq_rescue<<<2048, 256, 0, stream>>>(feat, code, esq, cnt, entries, out, acc);
}